// Round 15
// baseline (69.637 us; speedup 1.0000x reference)
//
#include <hip/hip_runtime.h>
#include <math.h>

// E8S codebook quantization via 32x32x16 bf16 MFMA pairs, exact 3-way split.
//   scores[r][c] = 2*X[r]·G[c] - ||G[c]||^2 ; idx = first-argmax over c.
// Exactness: G coords multiples of 0.25 (exact bf16); 2*X = h+m+l exact
// 3-term bf16 split; gn multiple of 0.5 < 16 (exact bf16, folded into K via
// gn * -1).  Tile = 32 codewords x 32 rows, kg = lane>>5:
//   stage1: A=coords, B=(kg? m : h)                   -> (h+m)·g
//   stage2: A=(kg? [gn,0..] : coords), B=(kg? [-1,0..] : l), C=stage1
// D layout: col=lane&31 (X row), cw_in_tile=(reg&3)+8*(reg>>2)+4*kg.
// R15: the loop's VALU stream must drop below the 128-cyc/tile matrix stream.
// (R7-R14 post-mortems: every schedule stuck at ~31us because "=&v" fresh
// tuples + per-tile max trees kept VALU ~= MFMA; both pipes half-fed.)
//  - MFMA scratch t0/t1 are "+v" TIED tuples declared once: fixed register
//    homes, no per-iteration re-allocation or rotation movs.
//  - Per tile: 4 MFMA + 32 independent v_max_f32 (elementwise running max
//    into dm0/dm1) - no tree, no cmp/sel in the loop.
//  - Tree + (val, group) tracking once per 8-tile group; packed u64 atomicMax
//    (enc_ord(score)<<32 | ~gid). Resolve rescans the winning group's <=8
//    tiles bit-identically, ascending -> smallest matching index ==
//    np.argmax first-max (group machinery validated in R11).

typedef short short8 __attribute__((ext_vector_type(8)));
typedef float f32x16 __attribute__((ext_vector_type(16)));

constexpr int NROWS  = 8192;
constexpr int NCW    = 55650;
constexpr int NT     = 1740;          // 32-codeword tiles
constexpr int NCWP   = NT * 32;       // 55680
constexpr int NCHUNK = 24;            // tile chunks (grid.y)
constexpr int RBLK   = 32;            // row blocks of 256 rows (grid.x)

// workspace layout (bytes)
// Gb: [NT][512 ushort]: per cw a 16-ushort record = [coords 0..7 | gn | 0 x7]
constexpr size_t OFF_GB = 0;
constexpr size_t OFF_XS = OFF_GB + (size_t)NT * 1024;   // ushort Xs[NROWS*4*8]
constexpr size_t OFF_BK = OFF_XS + (size_t)NROWS * 64;  // u64 best[NROWS]

__device__ inline unsigned short bf16_rne(float f) {
  unsigned int u = __float_as_uint(f);
  unsigned int r = u + 0x7FFFu + ((u >> 16) & 1u);
  return (unsigned short)(r >> 16);
}
__device__ inline float bf16_f(unsigned short h) {
  return __uint_as_float(((unsigned int)h) << 16);
}
__device__ inline unsigned int enc_ord(float f) {
  unsigned int u = __float_as_uint(f);
  return (u & 0x80000000u) ? ~u : (u | 0x80000000u);
}
__device__ inline float dec_ord(unsigned int e) {
  unsigned int u = (e & 0x80000000u) ? (e & 0x7FFFFFFFu) : ~e;
  return __uint_as_float(u);
}
__device__ inline float max16(const f32x16& d) {
  float t1 = fmaxf(fmaxf(d[0], d[1]), d[2]);
  float t2 = fmaxf(fmaxf(d[3], d[4]), d[5]);
  float t3 = fmaxf(fmaxf(d[6], d[7]), d[8]);
  float t4 = fmaxf(fmaxf(d[9], d[10]), d[11]);
  float t5 = fmaxf(fmaxf(d[12], d[13]), d[14]);
  float u1 = fmaxf(fmaxf(t1, t2), t3);
  float u2 = fmaxf(fmaxf(t4, t5), d[15]);
  return fmaxf(u1, u2);
}

__global__ __launch_bounds__(256) void e8_prep(
    const float* __restrict__ X, const float* __restrict__ G,
    const float* __restrict__ GN, unsigned short* __restrict__ Gb,
    unsigned short* __restrict__ Xs, unsigned long long* __restrict__ best) {
  int i = blockIdx.x * 256 + threadIdx.x;
  if (i < NCWP) {
    unsigned short g16[16];
    if (i < NCW) {
      for (int j = 0; j < 8; ++j) g16[j] = bf16_rne(G[(size_t)i*8+j]);
      g16[8] = bf16_rne(GN[i]);         // exact: multiple of 0.5, < 16
      for (int j = 9; j < 16; ++j) g16[j] = 0;
    } else {
      for (int j = 0; j < 8; ++j) g16[j] = 0;
      g16[8] = 0x7F7F;                  // bf16 max finite -> score ~ -3.4e38
      for (int j = 9; j < 16; ++j) g16[j] = 0;
    }
    uint4* dst = reinterpret_cast<uint4*>(Gb + (size_t)i * 16);
    dst[0] = *reinterpret_cast<uint4*>(&g16[0]);
    dst[1] = *reinterpret_cast<uint4*>(&g16[8]);
  } else if (i < NCWP + NROWS) {
    int r = i - NCWP;
    unsigned short hh[8], mm[8], ll[8], qq[8];
    for (int j = 0; j < 8; ++j) {
      float s = 2.0f * X[(size_t)r*8+j];           // exact
      unsigned short h = bf16_rne(s);  float r1 = s  - bf16_f(h);  // exact
      unsigned short m = bf16_rne(r1); float r2 = r1 - bf16_f(m);  // exact
      unsigned short l = bf16_rne(r2);             // residual after 3 terms = 0
      hh[j] = h; mm[j] = m; ll[j] = l;
      qq[j] = (j == 0) ? (unsigned short)0xBF80 : 0;  // -1.0
    }
    uint4* dst = reinterpret_cast<uint4*>(Xs + (size_t)r * 32);
    dst[0] = *reinterpret_cast<uint4*>(hh);
    dst[1] = *reinterpret_cast<uint4*>(mm);
    dst[2] = *reinterpret_cast<uint4*>(ll);
    dst[3] = *reinterpret_cast<uint4*>(qq);
    best[r] = 0ull;
  }
}

// 4 MFMAs for one 32cw x 64row tile-step. D0/D1 are TIED (+v) tuples: the
// register allocator keeps one fixed home across the whole loop (no fresh
// allocs / rotation copies). s_nops cover the MFMA->VALU read hazard
// (compiler can't see the writes inside asm; pattern validated R8-R12).
#define E8_MFMA(D0, D1, A1, A2)                                            \
  asm volatile(                                                            \
      "v_mfma_f32_32x32x16_bf16 %0, %2, %4, %6\n\t"                        \
      "v_mfma_f32_32x32x16_bf16 %1, %2, %5, %6\n\t"                        \
      "v_mfma_f32_32x32x16_bf16 %0, %3, %7, %0\n\t"                        \
      "v_mfma_f32_32x32x16_bf16 %1, %3, %8, %1\n\t"                        \
      "s_nop 7\n\t"                                                        \
      "s_nop 7"                                                            \
      : "+v"(D0), "+v"(D1)                                                 \
      : "v"(A1), "v"(A2), "v"(b10), "v"(b11), "v"(cz), "v"(b20), "v"(b21))

// Per block: 4 waves x 2 row-tiles = 256 rows, chunk of 72-73 cw-tiles.
// Grid 32x24 = 768 blocks = 3 blocks/CU = 3 waves/SIMD.
__global__ __launch_bounds__(256, 3) void e8_main(
    const unsigned short* __restrict__ Gb,
    const unsigned short* __restrict__ Xs,
    unsigned long long* __restrict__ best) {
  const int lane = threadIdx.x & 63;
  const int wave = threadIdx.x >> 6;
  const int kg = lane >> 5, l31 = lane & 31;
  const int rowbase = blockIdx.x * 256 + wave * 64;

  short8 b10, b11, b20, b21;
  {
    const size_t row0 = (size_t)rowbase + l31;
    const size_t row1 = row0 + 32;
    b10 = *reinterpret_cast<const short8*>(Xs + (row0*4 + kg)*8);
    b20 = *reinterpret_cast<const short8*>(Xs + (row0*4 + 2 + kg)*8);
    b11 = *reinterpret_cast<const short8*>(Xs + (row1*4 + kg)*8);
    b21 = *reinterpret_cast<const short8*>(Xs + (row1*4 + 2 + kg)*8);
  }
  asm("" : "+v"(b10), "+v"(b11), "+v"(b20), "+v"(b21));

  const int ct0 = blockIdx.y * NT / NCHUNK;
  const int ct1 = (blockIdx.y + 1) * NT / NCHUNK;

  f32x16 cz;
#pragma unroll
  for (int i = 0; i < 16; ++i) cz[i] = 0.0f;

  f32x16 dm0 = cz, dm1 = cz, t0 = cz, t1 = cz;   // fixed homes ("+v" tied)

  float bs0 = -INFINITY, bs1 = -INFINITY;
  int   bi0 = 0,         bi1 = 0;

  const unsigned short* p = Gb + (size_t)ct0 * 512 + (size_t)l31 * 16;
  const int koff = kg << 3;   // a2 slice: coords (kg=0) or [gn,0..] (kg=1)

  short8 a1 = *reinterpret_cast<const short8*>(p);
  short8 a2 = *reinterpret_cast<const short8*>(p + koff);

  int ct = ct0;
  while (ct < ct1) {
    const int gend0 = ((ct >> 3) + 1) << 3;
    const int gend  = (gend0 < ct1) ? gend0 : ct1;

    // first tile of group: MFMA straight into dm (overwrite = init)
    p += 512;
    {
      short8 n1 = *reinterpret_cast<const short8*>(p);
      short8 n2 = *reinterpret_cast<const short8*>(p + koff);
      E8_MFMA(dm0, dm1, a1, a2);
      a1 = n1; a2 = n2;
    }
    ++ct;
    for (; ct < gend; ++ct) {     // accumulate tiles into running max
      p += 512;
      short8 n1 = *reinterpret_cast<const short8*>(p);
      short8 n2 = *reinterpret_cast<const short8*>(p + koff);
      E8_MFMA(t0, t1, a1, a2);
#pragma unroll
      for (int i = 0; i < 16; ++i) {
        dm0[i] = fmaxf(dm0[i], t0[i]);
        dm1[i] = fmaxf(dm1[i], t1[i]);
      }
      a1 = n1; a2 = n2;
    }

    const int gid = (ct - 1) >> 3;      // global 8-tile group id (monotone)
    const float m0 = max16(dm0);
    const float m1 = max16(dm1);
    bi0 = (m0 > bs0) ? gid : bi0;       // strict > -> earliest group wins
    bs0 = fmaxf(bs0, m0);
    bi1 = (m1 > bs1) ? gid : bi1;
    bs1 = fmaxf(bs1, m1);
  }

  {
    unsigned long long key =
        ((unsigned long long)enc_ord(bs0) << 32) | (unsigned int)(~bi0);
    unsigned long long o = __shfl_xor(key, 32, 64);
    key = (o > key) ? o : key;          // merge the two kg half-sets of a row
    if (lane < 32) atomicMax(&best[(size_t)rowbase + l31], key);
  }
  {
    unsigned long long key =
        ((unsigned long long)enc_ord(bs1) << 32) | (unsigned int)(~bi1);
    unsigned long long o = __shfl_xor(key, 32, 64);
    key = (o > key) ? o : key;
    if (lane < 32) atomicMax(&best[(size_t)rowbase + 32 + l31], key);
  }
}

// 512 blocks x 4 waves; wave handles 4 rows of a half row-tile: re-run the
// bit-identical MFMA chain over the winning GROUP's <=8 tiles, take the
// smallest matching global index, write the output row (vals + idx).
__global__ __launch_bounds__(256) void e8_resolve(
    const unsigned short* __restrict__ Gb,
    const unsigned short* __restrict__ Xs, const float* __restrict__ G,
    const unsigned long long* __restrict__ best, float* __restrict__ out) {
  const int lane = threadIdx.x & 63;
  const int wave = threadIdx.x >> 6;
  const int kg = lane >> 5, l31 = lane & 31;
  const int rt   = blockIdx.x >> 1;       // 0..255 (32-row tile)
  const int half = blockIdx.x & 1;        // rows 0-15 / 16-31

  short8 b1, b2;
  {
    const size_t row = (size_t)rt * 32 + l31;
    b1 = *reinterpret_cast<const short8*>(Xs + (row*4 + kg)*8);
    b2 = *reinterpret_cast<const short8*>(Xs + (row*4 + 2 + kg)*8);
  }
  f32x16 cz;
#pragma unroll
  for (int i = 0; i < 16; ++i) cz[i] = 0.0f;

  const int jbeg = half * 16 + wave * 4;
  for (int j = jbeg; j < jbeg + 4; ++j) {
    const int srow = rt * 32 + j;
    const unsigned long long k = best[srow];
    const float sstar = dec_ord((unsigned int)(k >> 32));
    const int gwin = (int)(~(unsigned int)(k & 0xFFFFFFFFull));

    const int tb = gwin * 8;
    const int te = (tb + 8 < NT) ? tb + 8 : NT;
    int cand = 0x7FFFFFFF;
    for (int tt = tb; tt < te; ++tt) {
      const unsigned short* ga = Gb + (size_t)tt * 512 + (size_t)l31 * 16;
      short8 a1 = *reinterpret_cast<const short8*>(ga);
      short8 a2 = *reinterpret_cast<const short8*>(ga + (kg << 3));
      f32x16 d = __builtin_amdgcn_mfma_f32_32x32x16_bf16(a1, b1, cz, 0, 0, 0);
      d = __builtin_amdgcn_mfma_f32_32x32x16_bf16(a2, b2, d, 0, 0, 0);

      int tc = 0x0FFFFFFF;
#pragma unroll
      for (int r = 15; r >= 0; --r)     // descending -> smallest slot wins
        tc = (d[r] == sstar) ? ((r & 3) + 8 * (r >> 2)) : tc;
      const int gidx = tt * 32 + 4 * kg + tc;   // huge if no match
      cand = (gidx < cand) ? gidx : cand;       // tiles ascend -> first match
    }
    if (l31 != j) cand = 0x7FFFFFFF;    // only this row's two lanes count
    const int o = __shfl_xor(cand, 32, 64);
    cand = min(cand, o);
    if (lane == j) {
      const float4* g = reinterpret_cast<const float4*>(G + (size_t)cand * 8);
      float4 v0 = g[0], v1 = g[1];
      float4* od = reinterpret_cast<float4*>(out + (size_t)srow * 8);
      od[0] = v0; od[1] = v1;
      out[(size_t)NROWS * 8 + srow] = (float)(cand - 32768);
    }
  }
}

extern "C" void kernel_launch(void* const* d_in, const int* in_sizes, int n_in,
                              void* d_out, int out_size, void* d_ws, size_t ws_size,
                              hipStream_t stream) {
  const float* X  = (const float*)d_in[0];
  const float* G  = (const float*)d_in[1];
  const float* GN = (const float*)d_in[2];
  float* out = (float*)d_out;

  char* ws = (char*)d_ws;
  unsigned short*     Gb   = (unsigned short*)(ws + OFF_GB);
  unsigned short*     Xs   = (unsigned short*)(ws + OFF_XS);
  unsigned long long* best = (unsigned long long*)(ws + OFF_BK);

  e8_prep<<<(NCWP + NROWS + 255) / 256, 256, 0, stream>>>(X, G, GN, Gb, Xs, best);
  e8_main<<<dim3(RBLK, NCHUNK), 256, 0, stream>>>(Gb, Xs, best);
  e8_resolve<<<512, 256, 0, stream>>>(Gb, Xs, G, best, out);
}

// Round 16
// 47.374 us; speedup vs baseline: 1.4699x; 1.4699x over previous
//
#include <hip/hip_runtime.h>
#include <math.h>

// E8S codebook quantization via 32x32x16 bf16 MFMA pairs, exact 3-way split.
//   scores[r][c] = 2*X[r]·G[c] - ||G[c]||^2 ; idx = first-argmax over c.
// Exactness: G coords multiples of 0.25 (exact bf16); 2*X = h+m+l exact
// 3-term bf16 split; gn multiple of 0.5 < 16 (exact bf16, folded into K via
// gn * -1).  Tile = 32 codewords x 32 rows, kg = lane>>5:
//   stage1: A=coords, B=(kg? m : h)                   -> (h+m)·g
//   stage2: A=(kg? [gn,0..] : coords), B=(kg? [-1,0..] : l), C=stage1
// D layout: col=lane&31 (X row), cw_in_tile=(reg&3)+8*(reg>>2)+4*kg.
// R16: MEGA-ASM. R8-R15 proved the register allocator always homes f32x16
// accumulators in AGPRs with shuttle copies at every asm boundary (~100+
// hidden VALU/tile; VGPR_Count 32-72 while live set is 100+). Fix: the whole
// inner loop lives in inline asm on explicit physical registers:
//   v46,v47   : voffsets (tile stride 1024B)
//   v48-55    : a-frag buffer B       v56-63 : a-frag buffer A
//   v64-95    : d accum A (dA0,dA1)   v96-127: d accum B (dB0,dB1)
//   v128-159  : running max dm0,dm1   v160-163: bs0,bs1,bi0,bi1
// Per 8-tile group one unrolled asm: per tile {vmcnt(2) counted wait, 4 MFMA,
// 2 global_load (2-tile-ahead prefetch), 32 v_max of the PREVIOUS tile's d
// (overlaps MFMA latency)}; drain + 30-op tree + in-asm (score,group) track.
// State persists across asm blocks in clobbered regs. NT padded to 1744 ->
// 218 full groups of 8. Resolve rescans the winning group's 8 tiles
// bit-identically, ascending -> np.argmax first-max (validated R11/R15).

typedef short short8 __attribute__((ext_vector_type(8)));
typedef float f32x16 __attribute__((ext_vector_type(16)));

constexpr int NROWS  = 8192;
constexpr int NCW    = 55650;
constexpr int NT2    = 1744;          // padded tile count (218 groups of 8)
constexpr int NG     = 218;           // 8-tile groups
constexpr int NCWP2  = NT2 * 32;      // 55808
constexpr int NCHUNK = 24;            // group chunks (grid.y)
constexpr int RBLK   = 32;            // row blocks of 256 rows (grid.x)

// workspace layout (bytes)
constexpr size_t OFF_GB = 0;                              // [NT2][1024B]
constexpr size_t OFF_XS = OFF_GB + (size_t)NT2 * 1024;    // ushort Xs[NROWS*32]
constexpr size_t OFF_BK = OFF_XS + (size_t)NROWS * 64;    // u64 best[NROWS]

__device__ inline unsigned short bf16_rne(float f) {
  unsigned int u = __float_as_uint(f);
  unsigned int r = u + 0x7FFFu + ((u >> 16) & 1u);
  return (unsigned short)(r >> 16);
}
__device__ inline float bf16_f(unsigned short h) {
  return __uint_as_float(((unsigned int)h) << 16);
}
__device__ inline unsigned int enc_ord(float f) {
  unsigned int u = __float_as_uint(f);
  return (u & 0x80000000u) ? ~u : (u | 0x80000000u);
}
__device__ inline float dec_ord(unsigned int e) {
  unsigned int u = (e & 0x80000000u) ? (e & 0x7FFFFFFFu) : ~e;
  return __uint_as_float(u);
}

__global__ __launch_bounds__(256) void e8_prep(
    const float* __restrict__ X, const float* __restrict__ G,
    const float* __restrict__ GN, unsigned short* __restrict__ Gb,
    unsigned short* __restrict__ Xs, unsigned long long* __restrict__ best) {
  int i = blockIdx.x * 256 + threadIdx.x;
  if (i < NCWP2) {
    unsigned short g16[16];
    if (i < NCW) {
      for (int j = 0; j < 8; ++j) g16[j] = bf16_rne(G[(size_t)i*8+j]);
      g16[8] = bf16_rne(GN[i]);         // exact: multiple of 0.5, < 16
      for (int j = 9; j < 16; ++j) g16[j] = 0;
    } else {
      for (int j = 0; j < 8; ++j) g16[j] = 0;
      g16[8] = 0x7F7F;                  // bf16 max finite -> score ~ -3.4e38
      for (int j = 9; j < 16; ++j) g16[j] = 0;
    }
    uint4* dst = reinterpret_cast<uint4*>(Gb + (size_t)i * 16);
    dst[0] = *reinterpret_cast<uint4*>(&g16[0]);
    dst[1] = *reinterpret_cast<uint4*>(&g16[8]);
  } else if (i < NCWP2 + NROWS) {
    int r = i - NCWP2;
    unsigned short hh[8], mm[8], ll[8], qq[8];
    for (int j = 0; j < 8; ++j) {
      float s = 2.0f * X[(size_t)r*8+j];           // exact
      unsigned short h = bf16_rne(s);  float r1 = s  - bf16_f(h);  // exact
      unsigned short m = bf16_rne(r1); float r2 = r1 - bf16_f(m);  // exact
      unsigned short l = bf16_rne(r2);             // residual after 3 terms = 0
      hh[j] = h; mm[j] = m; ll[j] = l;
      qq[j] = (j == 0) ? (unsigned short)0xBF80 : 0;  // -1.0
    }
    uint4* dst = reinterpret_cast<uint4*>(Xs + (size_t)r * 32);
    dst[0] = *reinterpret_cast<uint4*>(hh);
    dst[1] = *reinterpret_cast<uint4*>(mm);
    dst[2] = *reinterpret_cast<uint4*>(ll);
    dst[3] = *reinterpret_cast<uint4*>(qq);
    best[r] = 0ull;
  }
}

// ---- mega-asm building blocks --------------------------------------------
#define MV(d, s) "v_mov_b32 v" #d ", v" #s "\n\t"
#define MX(d, s) "v_max_f32 v" #d ", v" #d ", v" #s "\n\t"

#define MOVA32 \
  MV(128,64) MV(129,65) MV(130,66) MV(131,67) MV(132,68) MV(133,69) \
  MV(134,70) MV(135,71) MV(136,72) MV(137,73) MV(138,74) MV(139,75) \
  MV(140,76) MV(141,77) MV(142,78) MV(143,79) MV(144,80) MV(145,81) \
  MV(146,82) MV(147,83) MV(148,84) MV(149,85) MV(150,86) MV(151,87) \
  MV(152,88) MV(153,89) MV(154,90) MV(155,91) MV(156,92) MV(157,93) \
  MV(158,94) MV(159,95)

#define MAXA32 \
  MX(128,64) MX(129,65) MX(130,66) MX(131,67) MX(132,68) MX(133,69) \
  MX(134,70) MX(135,71) MX(136,72) MX(137,73) MX(138,74) MX(139,75) \
  MX(140,76) MX(141,77) MX(142,78) MX(143,79) MX(144,80) MX(145,81) \
  MX(146,82) MX(147,83) MX(148,84) MX(149,85) MX(150,86) MX(151,87) \
  MX(152,88) MX(153,89) MX(154,90) MX(155,91) MX(156,92) MX(157,93) \
  MX(158,94) MX(159,95)

#define MAXB32 \
  MX(128,96)  MX(129,97)  MX(130,98)  MX(131,99)  MX(132,100) MX(133,101) \
  MX(134,102) MX(135,103) MX(136,104) MX(137,105) MX(138,106) MX(139,107) \
  MX(140,108) MX(141,109) MX(142,110) MX(143,111) MX(144,112) MX(145,113) \
  MX(146,114) MX(147,115) MX(148,116) MX(149,117) MX(150,118) MX(151,119) \
  MX(152,120) MX(153,121) MX(154,122) MX(155,123) MX(156,124) MX(157,125) \
  MX(158,126) MX(159,127)

#define TREE \
  MX(128,136) MX(129,137) MX(130,138) MX(131,139) \
  MX(132,140) MX(133,141) MX(134,142) MX(135,143) \
  MX(144,152) MX(145,153) MX(146,154) MX(147,155) \
  MX(148,156) MX(149,157) MX(150,158) MX(151,159) \
  MX(128,132) MX(129,133) MX(130,134) MX(131,135) \
  MX(144,148) MX(145,149) MX(146,150) MX(147,151) \
  MX(128,130) MX(129,131) MX(144,146) MX(145,147) \
  MX(128,129) MX(144,145)

#define TRACK \
  "v_cmp_gt_f32 vcc, v128, v160\n\t" \
  "v_cndmask_b32 v162, v162, %[gi], vcc\n\t" \
  "v_max_f32 v160, v160, v128\n\t" \
  "v_cmp_gt_f32 vcc, v144, v161\n\t" \
  "v_cndmask_b32 v163, v163, %[gi], vcc\n\t" \
  "v_max_f32 v161, v161, v144\n\t"

#define TILE_A \
  "s_waitcnt vmcnt(2)\n\t" \
  "v_mfma_f32_32x32x16_bf16 v[64:79], v[56:59], %[b10], %[cz]\n\t" \
  "v_mfma_f32_32x32x16_bf16 v[80:95], v[56:59], %[b11], %[cz]\n\t" \
  "v_mfma_f32_32x32x16_bf16 v[64:79], v[60:63], %[b20], v[64:79]\n\t" \
  "v_mfma_f32_32x32x16_bf16 v[80:95], v[60:63], %[b21], v[80:95]\n\t" \
  "global_load_dwordx4 v[56:59], v46, %[gb]\n\t" \
  "global_load_dwordx4 v[60:63], v47, %[gb]\n\t" \
  "v_add_u32 v46, 0x400, v46\n\t" \
  "v_add_u32 v47, 0x400, v47\n\t" \
  "s_nop 1\n\t"

#define TILE_B \
  "s_waitcnt vmcnt(2)\n\t" \
  "v_mfma_f32_32x32x16_bf16 v[96:111], v[48:51], %[b10], %[cz]\n\t" \
  "v_mfma_f32_32x32x16_bf16 v[112:127], v[48:51], %[b11], %[cz]\n\t" \
  "v_mfma_f32_32x32x16_bf16 v[96:111], v[52:55], %[b20], v[96:111]\n\t" \
  "v_mfma_f32_32x32x16_bf16 v[112:127], v[52:55], %[b21], v[112:127]\n\t" \
  "global_load_dwordx4 v[48:51], v46, %[gb]\n\t" \
  "global_load_dwordx4 v[52:55], v47, %[gb]\n\t" \
  "v_add_u32 v46, 0x400, v46\n\t" \
  "v_add_u32 v47, 0x400, v47\n\t" \
  "s_nop 1\n\t"

#define GROUP_ASM \
  TILE_A TILE_B MOVA32 TILE_A MAXB32 TILE_B MAXA32 \
  TILE_A MAXB32 TILE_B MAXA32 TILE_A MAXB32 TILE_B MAXA32 \
  "s_nop 1\n\t" MAXB32 TREE TRACK "s_nop 0"

#define CLOBS \
  "v46","v47","v48","v49","v50","v51","v52","v53","v54","v55", \
  "v56","v57","v58","v59","v60","v61","v62","v63","v64","v65", \
  "v66","v67","v68","v69","v70","v71","v72","v73","v74","v75", \
  "v76","v77","v78","v79","v80","v81","v82","v83","v84","v85", \
  "v86","v87","v88","v89","v90","v91","v92","v93","v94","v95", \
  "v96","v97","v98","v99","v100","v101","v102","v103","v104","v105", \
  "v106","v107","v108","v109","v110","v111","v112","v113","v114","v115", \
  "v116","v117","v118","v119","v120","v121","v122","v123","v124","v125", \
  "v126","v127","v128","v129","v130","v131","v132","v133","v134","v135", \
  "v136","v137","v138","v139","v140","v141","v142","v143","v144","v145", \
  "v146","v147","v148","v149","v150","v151","v152","v153","v154","v155", \
  "v156","v157","v158","v159","v160","v161","v162","v163"

// Per block: 4 waves x 2 row-tiles = 256 rows, chunk of 9-10 groups.
// Grid 32x24 = 768 blocks = 3 blocks/CU = 3 waves/SIMD (VGPR ~164 fits).
__global__ __launch_bounds__(256, 3) void e8_main(
    const unsigned short* __restrict__ Gb,
    const unsigned short* __restrict__ Xs,
    unsigned long long* __restrict__ best) {
  const int lane = threadIdx.x & 63;
  const int wave = threadIdx.x >> 6;
  const int kg = lane >> 5, l31 = lane & 31;
  const int rowbase = blockIdx.x * 256 + wave * 64;

  short8 b10, b11, b20, b21;
  {
    const size_t row0 = (size_t)rowbase + l31;
    const size_t row1 = row0 + 32;
    b10 = *reinterpret_cast<const short8*>(Xs + (row0*4 + kg)*8);
    b20 = *reinterpret_cast<const short8*>(Xs + (row0*4 + 2 + kg)*8);
    b11 = *reinterpret_cast<const short8*>(Xs + (row1*4 + kg)*8);
    b21 = *reinterpret_cast<const short8*>(Xs + (row1*4 + 2 + kg)*8);
  }
  asm("" : "+v"(b10), "+v"(b11), "+v"(b20), "+v"(b21));

  f32x16 cz;
#pragma unroll
  for (int i = 0; i < 16; ++i) cz[i] = 0.0f;

  const int g0 = blockIdx.y * NG / NCHUNK;
  const int g1 = (blockIdx.y + 1) * NG / NCHUNK;
  const unsigned long long gbv = (unsigned long long)Gb;

  unsigned voff1 = (unsigned)g0 * 8192u + (unsigned)l31 * 32u;
  unsigned voff2 = voff1 + (unsigned)kg * 16u;

  // prologue: init fixed-reg state; load tiles g0*8 and g0*8+1
  asm volatile(
      "v_mov_b32 v46, %[o1]\n\t"
      "v_mov_b32 v47, %[o2]\n\t"
      "v_mov_b32 v160, 0xff800000\n\t"
      "v_mov_b32 v161, 0xff800000\n\t"
      "v_mov_b32 v162, 0\n\t"
      "v_mov_b32 v163, 0\n\t"
      "global_load_dwordx4 v[56:59], v46, %[gb]\n\t"
      "global_load_dwordx4 v[60:63], v47, %[gb]\n\t"
      "v_add_u32 v46, 0x400, v46\n\t"
      "v_add_u32 v47, 0x400, v47\n\t"
      "global_load_dwordx4 v[48:51], v46, %[gb]\n\t"
      "global_load_dwordx4 v[52:55], v47, %[gb]\n\t"
      "v_add_u32 v46, 0x400, v46\n\t"
      "v_add_u32 v47, 0x400, v47\n\t"
      "s_waitcnt vmcnt(0)"
      :: [gb]"s"(gbv), [o1]"v"(voff1), [o2]"v"(voff2)
      : CLOBS, "memory");

  for (int g = g0; g < g1; ++g) {
    asm volatile(GROUP_ASM
        :: [gb]"s"(gbv), [gi]"v"(g), [b10]"v"(b10), [b11]"v"(b11),
           [b20]"v"(b20), [b21]"v"(b21), [cz]"v"(cz)
        : CLOBS, "vcc", "memory");
  }

  float bs0, bs1; int bi0, bi1;
  asm volatile(
      "s_waitcnt vmcnt(0)\n\t"
      "v_mov_b32 %0, v160\n\t"
      "v_mov_b32 %1, v161\n\t"
      "v_mov_b32 %2, v162\n\t"
      "v_mov_b32 %3, v163"
      : "=v"(bs0), "=v"(bs1), "=v"(bi0), "=v"(bi1) :: "memory");

  {
    unsigned long long key =
        ((unsigned long long)enc_ord(bs0) << 32) | (unsigned int)(~bi0);
    unsigned long long o = __shfl_xor(key, 32, 64);
    key = (o > key) ? o : key;          // merge the two kg half-sets of a row
    if (lane < 32) atomicMax(&best[(size_t)rowbase + l31], key);
  }
  {
    unsigned long long key =
        ((unsigned long long)enc_ord(bs1) << 32) | (unsigned int)(~bi1);
    unsigned long long o = __shfl_xor(key, 32, 64);
    key = (o > key) ? o : key;
    if (lane < 32) atomicMax(&best[(size_t)rowbase + 32 + l31], key);
  }
}

// 512 blocks x 4 waves; wave handles 4 rows of a half row-tile: re-run the
// bit-identical MFMA chain over the winning GROUP's 8 tiles, take the
// smallest matching global index, write the output row (vals + idx).
__global__ __launch_bounds__(256) void e8_resolve(
    const unsigned short* __restrict__ Gb,
    const unsigned short* __restrict__ Xs, const float* __restrict__ G,
    const unsigned long long* __restrict__ best, float* __restrict__ out) {
  const int lane = threadIdx.x & 63;
  const int wave = threadIdx.x >> 6;
  const int kg = lane >> 5, l31 = lane & 31;
  const int rt   = blockIdx.x >> 1;       // 0..255 (32-row tile)
  const int half = blockIdx.x & 1;        // rows 0-15 / 16-31

  short8 b1, b2;
  {
    const size_t row = (size_t)rt * 32 + l31;
    b1 = *reinterpret_cast<const short8*>(Xs + (row*4 + kg)*8);
    b2 = *reinterpret_cast<const short8*>(Xs + (row*4 + 2 + kg)*8);
  }
  f32x16 cz;
#pragma unroll
  for (int i = 0; i < 16; ++i) cz[i] = 0.0f;

  const int jbeg = half * 16 + wave * 4;
  for (int j = jbeg; j < jbeg + 4; ++j) {
    const int srow = rt * 32 + j;
    const unsigned long long k = best[srow];
    const float sstar = dec_ord((unsigned int)(k >> 32));
    const int gwin = (int)(~(unsigned int)(k & 0xFFFFFFFFull));

    const int tb = gwin * 8;
    int cand = 0x7FFFFFFF;
    for (int tt = tb; tt < tb + 8; ++tt) {
      const unsigned short* ga = Gb + (size_t)tt * 512 + (size_t)l31 * 16;
      short8 a1 = *reinterpret_cast<const short8*>(ga);
      short8 a2 = *reinterpret_cast<const short8*>(ga + (kg << 3));
      f32x16 d = __builtin_amdgcn_mfma_f32_32x32x16_bf16(a1, b1, cz, 0, 0, 0);
      d = __builtin_amdgcn_mfma_f32_32x32x16_bf16(a2, b2, d, 0, 0, 0);

      int tc = 0x0FFFFFFF;
#pragma unroll
      for (int r = 15; r >= 0; --r)     // descending -> smallest slot wins
        tc = (d[r] == sstar) ? ((r & 3) + 8 * (r >> 2)) : tc;
      const int gidx = tt * 32 + 4 * kg + tc;   // huge if no match
      cand = (gidx < cand) ? gidx : cand;       // tiles ascend -> first match
    }
    if (l31 != j) cand = 0x7FFFFFFF;    // only this row's two lanes count
    const int o = __shfl_xor(cand, 32, 64);
    cand = min(cand, o);
    if (lane == j) {
      const float4* g = reinterpret_cast<const float4*>(G + (size_t)cand * 8);
      float4 v0 = g[0], v1 = g[1];
      float4* od = reinterpret_cast<float4*>(out + (size_t)srow * 8);
      od[0] = v0; od[1] = v1;
      out[(size_t)NROWS * 8 + srow] = (float)(cand - 32768);
    }
  }
}

extern "C" void kernel_launch(void* const* d_in, const int* in_sizes, int n_in,
                              void* d_out, int out_size, void* d_ws, size_t ws_size,
                              hipStream_t stream) {
  const float* X  = (const float*)d_in[0];
  const float* G  = (const float*)d_in[1];
  const float* GN = (const float*)d_in[2];
  float* out = (float*)d_out;

  char* ws = (char*)d_ws;
  unsigned short*     Gb   = (unsigned short*)(ws + OFF_GB);
  unsigned short*     Xs   = (unsigned short*)(ws + OFF_XS);
  unsigned long long* best = (unsigned long long*)(ws + OFF_BK);

  e8_prep<<<(NCWP2 + NROWS) / 256, 256, 0, stream>>>(X, G, GN, Gb, Xs, best);
  e8_main<<<dim3(RBLK, NCHUNK), 256, 0, stream>>>(Gb, Xs, best);
  e8_resolve<<<512, 256, 0, stream>>>(Gb, Xs, G, best, out);
}

// Round 17
// 44.996 us; speedup vs baseline: 1.5476x; 1.0528x over previous
//
#include <hip/hip_runtime.h>
#include <math.h>

// E8S codebook quantization via 16x16x32 bf16 MFMA, exact 3-way split.
//   scores[r][c] = 2*X[r]·G[c] - ||G[c]||^2 ; idx = first-argmax over c.
// Exactness: G coords multiples of 0.25 (exact bf16); 2*X = h+m+l exact
// 3-term bf16 split; gn multiple of 0.5 < 16 (exact bf16). K=32 = 4 groups
// of 8 (kg=lane>>4): {h,m,l}x coords + {-1,0..}x{gn,0..}. C = 0. ONE MFMA
// per 16x16 score tile -> NO C-operand chain between MFMAs.
// D layout (R4-R6, absmax-0 validated): col=lane&15 (X row),
// cw_in_tile = kg*4 + reg.
// R17: R7-R16 post-mortem: MfmaUtil x dur == MFMA-pipe floor (~11us) in every
// schedule -> waves stall ~200cyc inside each 32x32 tile on the stage2 MFMA
// whose C input is stage1's D (hardware dependent-MFMA latency; 3 waves can't
// cover it). 16x16x32 folds all 4 K-groups into one independent MFMA ->
// back-to-back issue at ~19.4cyc II. Mega-asm fixed regs (R16 discipline):
//   v40 voff | v44-47/v48-51 A dbuf | v52-55 cz | v56-71 B (4 row-tiles)
//   v72-87 dA | v88-103 dB | v104-119 dm | v120-123 bs | v124-127 bi
// Per tile: vmcnt(1), 4 indep MFMA, 1 A-load (2-deep), 16 v_max (prev tile).
// Group of 8 tiles -> tree + (score,group) track; packed u64 atomicMax
// (enc_ord<<32 | ~gid). Resolve rescans winning group's 8 tiles
// bit-identically, ascending -> np.argmax first-max (validated R11/R16).

typedef short short8 __attribute__((ext_vector_type(8)));
typedef float f32x4  __attribute__((ext_vector_type(4)));

constexpr int NROWS  = 8192;
constexpr int NCW    = 55650;
constexpr int NT16   = 3488;          // 16-codeword tiles (436 groups of 8)
constexpr int NG     = 436;           // 8-tile groups (128 cw each)
constexpr int NCWP2  = NT16 * 16;     // 55808
constexpr int NCHUNK = 32;            // group chunks (grid.y)
constexpr int RBLK   = 32;            // row blocks of 256 rows (grid.x)

// workspace layout (bytes). Gb: per cw a 32B record [coords 8bf16 | gn,0x7].
constexpr size_t OFF_GB = 0;                              // NCWP2*32 B
constexpr size_t OFF_XS = OFF_GB + (size_t)NCWP2 * 32;    // ushort Xs[NROWS*32]
constexpr size_t OFF_BK = OFF_XS + (size_t)NROWS * 64;    // u64 best[NROWS]

__device__ inline unsigned short bf16_rne(float f) {
  unsigned int u = __float_as_uint(f);
  unsigned int r = u + 0x7FFFu + ((u >> 16) & 1u);
  return (unsigned short)(r >> 16);
}
__device__ inline float bf16_f(unsigned short h) {
  return __uint_as_float(((unsigned int)h) << 16);
}
__device__ inline unsigned int enc_ord(float f) {
  unsigned int u = __float_as_uint(f);
  return (u & 0x80000000u) ? ~u : (u | 0x80000000u);
}
__device__ inline float dec_ord(unsigned int e) {
  unsigned int u = (e & 0x80000000u) ? (e & 0x7FFFFFFFu) : ~e;
  return __uint_as_float(u);
}

__global__ __launch_bounds__(256) void e8_prep(
    const float* __restrict__ X, const float* __restrict__ G,
    const float* __restrict__ GN, unsigned short* __restrict__ Gb,
    unsigned short* __restrict__ Xs, unsigned long long* __restrict__ best) {
  int i = blockIdx.x * 256 + threadIdx.x;
  if (i < NCWP2) {
    unsigned short g16[16];
    if (i < NCW) {
      for (int j = 0; j < 8; ++j) g16[j] = bf16_rne(G[(size_t)i*8+j]);
      g16[8] = bf16_rne(GN[i]);         // exact: multiple of 0.5, < 16
      for (int j = 9; j < 16; ++j) g16[j] = 0;
    } else {
      for (int j = 0; j < 8; ++j) g16[j] = 0;
      g16[8] = 0x7F7F;                  // bf16 max finite -> score ~ -3.4e38
      for (int j = 9; j < 16; ++j) g16[j] = 0;
    }
    uint4* dst = reinterpret_cast<uint4*>(Gb + (size_t)i * 16);
    dst[0] = *reinterpret_cast<uint4*>(&g16[0]);
    dst[1] = *reinterpret_cast<uint4*>(&g16[8]);
  } else if (i < NCWP2 + NROWS) {
    int r = i - NCWP2;
    unsigned short hh[8], mm[8], ll[8], qq[8];
    for (int j = 0; j < 8; ++j) {
      float s = 2.0f * X[(size_t)r*8+j];           // exact
      unsigned short h = bf16_rne(s);  float r1 = s  - bf16_f(h);  // exact
      unsigned short m = bf16_rne(r1); float r2 = r1 - bf16_f(m);  // exact
      unsigned short l = bf16_rne(r2);             // residual after 3 terms = 0
      hh[j] = h; mm[j] = m; ll[j] = l;
      qq[j] = (j == 0) ? (unsigned short)0xBF80 : 0;  // -1.0
    }
    uint4* dst = reinterpret_cast<uint4*>(Xs + (size_t)r * 32);
    dst[0] = *reinterpret_cast<uint4*>(hh);
    dst[1] = *reinterpret_cast<uint4*>(mm);
    dst[2] = *reinterpret_cast<uint4*>(ll);
    dst[3] = *reinterpret_cast<uint4*>(qq);
    best[r] = 0ull;
  }
}

// ---- mega-asm building blocks ---------------------------------------------
#define MV(d, s) "v_mov_b32 v" #d ", v" #s "\n\t"
#define MX(d, s) "v_max_f32 v" #d ", v" #d ", v" #s "\n\t"

// one 16cw tile, even slot: 4 independent MFMAs into dA; prefetch A(t+2).
#define T16A \
  "s_waitcnt vmcnt(1)\n\t" \
  "v_mfma_f32_16x16x32_bf16 v[72:75],  v[44:47], v[56:59], v[52:55]\n\t" \
  "v_mfma_f32_16x16x32_bf16 v[76:79],  v[44:47], v[60:63], v[52:55]\n\t" \
  "v_mfma_f32_16x16x32_bf16 v[80:83],  v[44:47], v[64:67], v[52:55]\n\t" \
  "v_mfma_f32_16x16x32_bf16 v[84:87],  v[44:47], v[68:71], v[52:55]\n\t" \
  "global_load_dwordx4 v[44:47], v40, %[gb]\n\t" \
  "v_add_u32 v40, 0x200, v40\n\t"

// odd slot: into dB, A-buf v48.
#define T16B \
  "s_waitcnt vmcnt(1)\n\t" \
  "v_mfma_f32_16x16x32_bf16 v[88:91],   v[48:51], v[56:59], v[52:55]\n\t" \
  "v_mfma_f32_16x16x32_bf16 v[92:95],   v[48:51], v[60:63], v[52:55]\n\t" \
  "v_mfma_f32_16x16x32_bf16 v[96:99],   v[48:51], v[64:67], v[52:55]\n\t" \
  "v_mfma_f32_16x16x32_bf16 v[100:103], v[48:51], v[68:71], v[52:55]\n\t" \
  "global_load_dwordx4 v[48:51], v40, %[gb]\n\t" \
  "v_add_u32 v40, 0x200, v40\n\t"

#define MOV16 \
  MV(104,72) MV(105,73) MV(106,74) MV(107,75) MV(108,76) MV(109,77) \
  MV(110,78) MV(111,79) MV(112,80) MV(113,81) MV(114,82) MV(115,83) \
  MV(116,84) MV(117,85) MV(118,86) MV(119,87)

#define MAXA16 \
  MX(104,72) MX(105,73) MX(106,74) MX(107,75) MX(108,76) MX(109,77) \
  MX(110,78) MX(111,79) MX(112,80) MX(113,81) MX(114,82) MX(115,83) \
  MX(116,84) MX(117,85) MX(118,86) MX(119,87)

#define MAXB16 \
  MX(104,88)  MX(105,89)  MX(106,90)  MX(107,91)  MX(108,92)  MX(109,93) \
  MX(110,94)  MX(111,95)  MX(112,96)  MX(113,97)  MX(114,98)  MX(115,99) \
  MX(116,100) MX(117,101) MX(118,102) MX(119,103)

// per row-tile: 3-op tree over dm quad, then (score,group) track.
#define TREETRACK \
  MX(104,105) MX(106,107) MX(108,109) MX(110,111) \
  MX(112,113) MX(114,115) MX(116,117) MX(118,119) \
  MX(104,106) MX(108,110) MX(112,114) MX(116,118) \
  "v_cmp_gt_f32 vcc, v104, v120\n\t" \
  "v_cndmask_b32 v124, v124, %[gi], vcc\n\t" \
  "v_max_f32 v120, v120, v104\n\t" \
  "v_cmp_gt_f32 vcc, v108, v121\n\t" \
  "v_cndmask_b32 v125, v125, %[gi], vcc\n\t" \
  "v_max_f32 v121, v121, v108\n\t" \
  "v_cmp_gt_f32 vcc, v112, v122\n\t" \
  "v_cndmask_b32 v126, v126, %[gi], vcc\n\t" \
  "v_max_f32 v122, v122, v112\n\t" \
  "v_cmp_gt_f32 vcc, v116, v123\n\t" \
  "v_cndmask_b32 v127, v127, %[gi], vcc\n\t" \
  "v_max_f32 v123, v123, v116\n\t"

#define GROUP16 \
  T16A T16B MOV16 T16A MAXB16 T16B MAXA16 \
  T16A MAXB16 T16B MAXA16 T16A MAXB16 T16B MAXA16 \
  "s_nop 7\n\t" "s_nop 7\n\t" MAXB16 TREETRACK "s_nop 0"

#define CLOBS \
  "v40","v41","v42","v43","v44","v45","v46","v47","v48","v49", \
  "v50","v51","v52","v53","v54","v55","v56","v57","v58","v59", \
  "v60","v61","v62","v63","v64","v65","v66","v67","v68","v69", \
  "v70","v71","v72","v73","v74","v75","v76","v77","v78","v79", \
  "v80","v81","v82","v83","v84","v85","v86","v87","v88","v89", \
  "v90","v91","v92","v93","v94","v95","v96","v97","v98","v99", \
  "v100","v101","v102","v103","v104","v105","v106","v107","v108","v109", \
  "v110","v111","v112","v113","v114","v115","v116","v117","v118","v119", \
  "v120","v121","v122","v123","v124","v125","v126","v127"

// Per block: 4 waves x 4 row-tiles(16) = 256 rows, chunk of 13-14 groups.
// Grid 32x32 = 1024 blocks; target 4 waves/SIMD (VGPR <= ~128).
__global__ __launch_bounds__(256, 4) void e8_main(
    const unsigned short* __restrict__ Gb,
    const unsigned short* __restrict__ Xs,
    unsigned long long* __restrict__ best) {
  const int lane = threadIdx.x & 63;
  const int wave = threadIdx.x >> 6;
  const int l15 = lane & 15, kg = lane >> 4;
  const int rowbase = blockIdx.x * 256 + wave * 64;

  const int g0 = blockIdx.y * NG / NCHUNK;
  const int g1 = (blockIdx.y + 1) * NG / NCHUNK;
  const unsigned long long gbv = (unsigned long long)Gb;
  const unsigned long long xsv = (unsigned long long)Xs;

  // A voffset: tile record = 32B/cw x 16 cw = 512B; kg<=2 -> coords slice,
  // kg==3 -> gn slice (+16B). B voffset: row*64B + kg*16B.
  unsigned avo = (unsigned)g0 * 4096u + (unsigned)l15 * 32u +
                 (kg == 3 ? 16u : 0u);
  unsigned bvo = (unsigned)(rowbase + l15) * 64u + (unsigned)kg * 16u;

  // prologue: cz=0, bs=-inf, bi=0; load 4 B-frags + A0,A1; drain.
  asm volatile(
      "v_mov_b32 v40, %[ao]\n\t"
      "v_mov_b32 v52, 0\n\t" "v_mov_b32 v53, 0\n\t"
      "v_mov_b32 v54, 0\n\t" "v_mov_b32 v55, 0\n\t"
      "v_mov_b32 v120, 0xff800000\n\t" "v_mov_b32 v121, 0xff800000\n\t"
      "v_mov_b32 v122, 0xff800000\n\t" "v_mov_b32 v123, 0xff800000\n\t"
      "v_mov_b32 v124, 0\n\t" "v_mov_b32 v125, 0\n\t"
      "v_mov_b32 v126, 0\n\t" "v_mov_b32 v127, 0\n\t"
      "global_load_dwordx4 v[56:59], %[bo], %[xs]\n\t"
      "global_load_dwordx4 v[60:63], %[bo], %[xs] offset:1024\n\t"
      "global_load_dwordx4 v[64:67], %[bo], %[xs] offset:2048\n\t"
      "global_load_dwordx4 v[68:71], %[bo], %[xs] offset:3072\n\t"
      "global_load_dwordx4 v[44:47], v40, %[gb]\n\t"
      "v_add_u32 v40, 0x200, v40\n\t"
      "global_load_dwordx4 v[48:51], v40, %[gb]\n\t"
      "v_add_u32 v40, 0x200, v40\n\t"
      "s_waitcnt vmcnt(0)"
      :: [gb]"s"(gbv), [xs]"s"(xsv), [ao]"v"(avo), [bo]"v"(bvo)
      : CLOBS, "memory");

  for (int g = g0; g < g1; ++g) {
    asm volatile(GROUP16
        :: [gb]"s"(gbv), [gi]"v"(g)
        : CLOBS, "vcc", "memory");
  }

  float bs0, bs1, bs2, bs3; int bi0, bi1, bi2, bi3;
  asm volatile(
      "s_waitcnt vmcnt(0)\n\t"
      "v_mov_b32 %0, v120\n\t" "v_mov_b32 %1, v121\n\t"
      "v_mov_b32 %2, v122\n\t" "v_mov_b32 %3, v123\n\t"
      "v_mov_b32 %4, v124\n\t" "v_mov_b32 %5, v125\n\t"
      "v_mov_b32 %6, v126\n\t" "v_mov_b32 %7, v127"
      : "=v"(bs0), "=v"(bs1), "=v"(bs2), "=v"(bs3),
        "=v"(bi0), "=v"(bi1), "=v"(bi2), "=v"(bi3) :: "memory");

  const float bsa[4] = {bs0, bs1, bs2, bs3};
  const int   bia[4] = {bi0, bi1, bi2, bi3};
#pragma unroll
  for (int t = 0; t < 4; ++t) {
    unsigned long long key =
        ((unsigned long long)enc_ord(bsa[t]) << 32) | (unsigned int)(~bia[t]);
    unsigned long long o = __shfl_xor(key, 16, 64);
    key = (o > key) ? o : key;          // merge the 4 kg quads of a row
    o = __shfl_xor(key, 32, 64);
    key = (o > key) ? o : key;
    if (lane < 16)
      atomicMax(&best[(size_t)rowbase + t * 16 + l15], key);
  }
}

// 512 blocks x 4 waves; block = one 16-row tile, wave handles 4 rows:
// re-run the bit-identical MFMA over the winning GROUP's 8 tiles, take the
// smallest matching global index, write vals + idx.
__global__ __launch_bounds__(256) void e8_resolve(
    const unsigned short* __restrict__ Gb,
    const unsigned short* __restrict__ Xs, const float* __restrict__ G,
    const unsigned long long* __restrict__ best, float* __restrict__ out) {
  const int lane = threadIdx.x & 63;
  const int wave = threadIdx.x >> 6;
  const int l15 = lane & 15, kg = lane >> 4;
  const int rt = blockIdx.x;              // 0..511 (16-row tile)

  short8 b;
  {
    const size_t row = (size_t)rt * 16 + l15;
    b = *reinterpret_cast<const short8*>(Xs + (row*4 + kg)*8);
  }
  f32x4 cz = {0.f, 0.f, 0.f, 0.f};

  for (int j = wave * 4; j < wave * 4 + 4; ++j) {
    const int srow = rt * 16 + j;
    const unsigned long long k = best[srow];
    const float sstar = dec_ord((unsigned int)(k >> 32));
    const int gwin = (int)(~(unsigned int)(k & 0xFFFFFFFFull));

    const int tb = gwin * 8;
    int cand = 0x7FFFFFFF;
    for (int tt = tb; tt < tb + 8; ++tt) {
      const unsigned short* ga =
          Gb + (size_t)tt * 256 + (size_t)l15 * 16 + (kg == 3 ? 8 : 0);
      short8 a = *reinterpret_cast<const short8*>(ga);
      f32x4 d = __builtin_amdgcn_mfma_f32_16x16x32_bf16(a, b, cz, 0, 0, 0);

      int tc = 0x0FFFFFFF;
#pragma unroll
      for (int r = 3; r >= 0; --r)      // descending -> smallest slot wins
        tc = (d[r] == sstar) ? r : tc;
      const int gidx = tt * 16 + kg * 4 + tc;   // huge if no match
      cand = (gidx < cand) ? gidx : cand;       // tiles ascend -> first match
    }
    if (l15 != j) cand = 0x7FFFFFFF;    // only this row's 4 lanes count
    int o = __shfl_xor(cand, 16, 64); cand = min(cand, o);
    o = __shfl_xor(cand, 32, 64);     cand = min(cand, o);
    if (lane == j) {
      const float4* g = reinterpret_cast<const float4*>(G + (size_t)cand * 8);
      float4 v0 = g[0], v1 = g[1];
      float4* od = reinterpret_cast<float4*>(out + (size_t)srow * 8);
      od[0] = v0; od[1] = v1;
      out[(size_t)NROWS * 8 + srow] = (float)(cand - 32768);
    }
  }
}

extern "C" void kernel_launch(void* const* d_in, const int* in_sizes, int n_in,
                              void* d_out, int out_size, void* d_ws, size_t ws_size,
                              hipStream_t stream) {
  const float* X  = (const float*)d_in[0];
  const float* G  = (const float*)d_in[1];
  const float* GN = (const float*)d_in[2];
  float* out = (float*)d_out;

  char* ws = (char*)d_ws;
  unsigned short*     Gb   = (unsigned short*)(ws + OFF_GB);
  unsigned short*     Xs   = (unsigned short*)(ws + OFF_XS);
  unsigned long long* best = (unsigned long long*)(ws + OFF_BK);

  e8_prep<<<(NCWP2 + NROWS + 255) / 256, 256, 0, stream>>>(X, G, GN, Gb, Xs, best);
  e8_main<<<dim3(RBLK, NCHUNK), 256, 0, stream>>>(Gb, Xs, best);
  e8_resolve<<<512, 256, 0, stream>>>(Gb, Xs, G, best, out);
}